// Round 9
// baseline (111.018 us; speedup 1.0000x reference)
//
#include <hip/hip_runtime.h>

// 16-step spike recurrence, elementwise.
// z_t = (v_t > T_t) since (v-T)/(|v|+1) > 0 <=> v > T (denominator >= 1).
// R9: A/B vs R8 — identical except PLAIN stores instead of nontemporal.
// Rationale: FETCH_SIZE was ~131 MB in every round regardless of nt, so
// "nt protects L3 for x" is falsified; the fill µbench shows cached writes
// sustain 7 TB/s, and nt's store-path throughput was never isolated.
//   z = clamp(fma(v, 2^40, -T*2^40))   -- v_pk_fma_f32 ... clamp
// 3 pk-instr per 2 elems per step; exact-cover 16384 blocks, 4x f32x4/thread.

typedef float f32x2 __attribute__((ext_vector_type(2)));
typedef float f32x4 __attribute__((ext_vector_type(4)));

static constexpr float kBIG = 1099511627776.0f;  // 2^40 (exact scale)

static constexpr float kH[16] = {
    -0.73437643f, 3.319645f,   2.1290164f,  3.6901689f,
    3.302721f,    3.2154958f,  2.9151256f,  3.1718695f,
    3.1084518f,   2.6179547f,  2.235003f,   1.2864777f,
    0.52327204f, -0.08344932f, -1.8249638f, 3.0859442f};

static constexpr float kD[16] = {
    3.3848417f, -0.07072583f, 3.691287f,   3.3074934f,
    3.2120926f,  2.9196491f,  3.1727686f,  3.1054153f,
    2.621943f,   2.2355895f,  1.2878408f,  0.52468026f,
    0.12632068f, 0.14482783f, 0.3153498f,  0.13054803f};

static constexpr float kT[16] = {
    3.1538513f, -1.0211663f,  1.3714716f,  1.0718397f,
    1.0049332f,  0.68078244f, 1.0151638f,  0.8858697f,
    0.4037103f,  0.01490025f, -0.90781677f, -1.6859558f,
    -1.9241625f, -2.0441303f, 0.279356f,   0.1315174f};

__device__ __forceinline__ f32x2 pk_fma(f32x2 a, f32x2 b, f32x2 c) {
    f32x2 d;
    asm("v_pk_fma_f32 %0, %1, %2, %3" : "=v"(d) : "v"(a), "v"(b), "v"(c));
    return d;
}

__device__ __forceinline__ f32x2 pk_fma_clamp(f32x2 a, f32x2 b, f32x2 c) {
    f32x2 d;
    asm("v_pk_fma_f32 %0, %1, %2, %3 clamp" : "=v"(d) : "v"(a), "v"(b), "v"(c));
    return d;
}

// Process 8 f32x2 pairs (16 elems) through all 16 steps; constants
// amortize across the 24 pk-ops per step.
__device__ __forceinline__ void spike8(f32x2 v[8], f32x2 o[8]) {
    const f32x2 big = {kBIG, kBIG};
    f32x2 z[8];
    {   // t = 0: z_{-1}=0 so v unchanged; o = z*D0.
        const f32x2 ts = {-kT[0] * kBIG, -kT[0] * kBIG};
        const f32x2 dd = {kD[0], kD[0]};
        const f32x2 zz = {0.0f, 0.0f};
#pragma unroll
        for (int c = 0; c < 8; ++c) {
            z[c] = pk_fma_clamp(v[c], big, ts);   // z = (v>T0)
            o[c] = pk_fma(z[c], dd, zz);          // o = z*D0 (exact)
        }
    }
#pragma unroll
    for (int t = 1; t < 16; ++t) {
        const f32x2 nh = {-kH[t], -kH[t]};
        const f32x2 ts = {-kT[t] * kBIG, -kT[t] * kBIG};
        const f32x2 dd = {kD[t], kD[t]};
#pragma unroll
        for (int c = 0; c < 8; ++c) {
            v[c] = pk_fma(z[c], nh, v[c]);        // v -= z_{t-1}*H[t] (exact)
            z[c] = pk_fma_clamp(v[c], big, ts);   // z = (v>T[t])
            o[c] = pk_fma(z[c], dd, o[c]);        // o += z*D[t]
        }
    }
}

// Exact-cover fast path: each thread owns 4 f32x4 at stride T.
__global__ __launch_bounds__(256) void spike_kernel(const f32x4* __restrict__ x,
                                                    f32x4* __restrict__ out) {
    const int T = gridDim.x * blockDim.x;
    const int i = blockIdx.x * blockDim.x + threadIdx.x;

    f32x4 a0 = x[i];
    f32x4 a1 = x[i + T];
    f32x4 a2 = x[i + 2 * T];
    f32x4 a3 = x[i + 3 * T];

    f32x2 v[8] = {a0.xy, a0.zw, a1.xy, a1.zw, a2.xy, a2.zw, a3.xy, a3.zw};
    f32x2 o[8];
    spike8(v, o);

    f32x4 r0 = {o[0].x, o[0].y, o[1].x, o[1].y};
    f32x4 r1 = {o[2].x, o[2].y, o[3].x, o[3].y};
    f32x4 r2 = {o[4].x, o[4].y, o[5].x, o[5].y};
    f32x4 r3 = {o[6].x, o[6].y, o[7].x, o[7].y};

    out[i] = r0;
    out[i + T] = r1;
    out[i + 2 * T] = r2;
    out[i + 3 * T] = r3;
}

// Generic fallback (any n4), plain math — reference-exact.
__device__ __forceinline__ float spike_chain(float v) {
    float z = (v > kT[0]) ? 1.0f : 0.0f;
    float out = z * kD[0];
#pragma unroll
    for (int t = 1; t < 16; ++t) {
        v = fmaf(-z, kH[t], v);
        z = (v > kT[t]) ? 1.0f : 0.0f;
        out = fmaf(z, kD[t], out);
    }
    return out;
}

__global__ __launch_bounds__(256) void spike_generic(const f32x4* __restrict__ x,
                                                     f32x4* __restrict__ out,
                                                     int n4) {
    const int T = gridDim.x * blockDim.x;
    int i = blockIdx.x * blockDim.x + threadIdx.x;
    for (; i < n4; i += T) {
        f32x4 a = x[i];
        f32x4 r;
        r.x = spike_chain(a.x);
        r.y = spike_chain(a.y);
        r.z = spike_chain(a.z);
        r.w = spike_chain(a.w);
        out[i] = r;
    }
}

extern "C" void kernel_launch(void* const* d_in, const int* in_sizes, int n_in,
                              void* d_out, int out_size, void* d_ws, size_t ws_size,
                              hipStream_t stream) {
    const float* x = (const float*)d_in[0];
    float* out = (float*)d_out;
    int n = in_sizes[0];          // 16*4096*1024 = 67,108,864
    int n4 = n >> 2;              // 16,777,216 float4

    const int block = 256;
    const int per_thread = 4;     // f32x4 per thread

    if (n4 % (block * per_thread) == 0) {
        int grid = n4 / (block * per_thread);   // 16384 for the bench shape
        spike_kernel<<<grid, block, 0, stream>>>(
            (const f32x4*)x, (f32x4*)out);
    } else {
        int grid = (n4 + block - 1) / block;
        if (grid > 4096) grid = 4096;
        spike_generic<<<grid, block, 0, stream>>>(
            (const f32x4*)x, (f32x4*)out, n4);
    }
}

// Round 10
// 82.703 us; speedup vs baseline: 1.3424x; 1.3424x over previous
//
#include <hip/hip_runtime.h>

// 16-step spike recurrence, elementwise.
// z_t = (v_t > T_t) since (v-T)/(|v|+1) > 0 <=> v > T (denominator >= 1).
// R10: R8 (nt stores, winning config) + per-step constants moved to SGPR
// operands ("s" asm constraints). R9's A/B showed plain stores cost +27us,
// so nt stores restored. VGPR=32 in R8 proved the compiler serialized the
// 8 chains and re-broadcast constants as v_mov per chain per step (~50% of
// VALU issue); SGPR constants put that on the scalar pipe instead.
//   z = clamp(fma(v, 2^40, -T*2^40))   -- v_pk_fma_f32 ... clamp
// Exact-cover 16384 blocks, 4x f32x4 per thread.

typedef float f32x2 __attribute__((ext_vector_type(2)));
typedef float f32x4 __attribute__((ext_vector_type(4)));

static constexpr float kBIG = 1099511627776.0f;  // 2^40 (exact scale)

static constexpr float kH[16] = {
    -0.73437643f, 3.319645f,   2.1290164f,  3.6901689f,
    3.302721f,    3.2154958f,  2.9151256f,  3.1718695f,
    3.1084518f,   2.6179547f,  2.235003f,   1.2864777f,
    0.52327204f, -0.08344932f, -1.8249638f, 3.0859442f};

static constexpr float kD[16] = {
    3.3848417f, -0.07072583f, 3.691287f,   3.3074934f,
    3.2120926f,  2.9196491f,  3.1727686f,  3.1054153f,
    2.621943f,   2.2355895f,  1.2878408f,  0.52468026f,
    0.12632068f, 0.14482783f, 0.3153498f,  0.13054803f};

static constexpr float kT[16] = {
    3.1538513f, -1.0211663f,  1.3714716f,  1.0718397f,
    1.0049332f,  0.68078244f, 1.0151638f,  0.8858697f,
    0.4037103f,  0.01490025f, -0.90781677f, -1.6859558f,
    -1.9241625f, -2.0441303f, 0.279356f,   0.1315174f};

// a,c in VGPRs; b is a wave-uniform constant pair in SGPRs (scalar pipe).
__device__ __forceinline__ f32x2 pk_fma_s(f32x2 a, f32x2 b, f32x2 c) {
    f32x2 d;
    asm("v_pk_fma_f32 %0, %1, %2, %3" : "=v"(d) : "v"(a), "s"(b), "v"(c));
    return d;
}

// z = clamp(a*b + c): a,b in VGPRs (b = hoisted 2^40 pair), c SGPR constant.
__device__ __forceinline__ f32x2 pk_fma_clamp_s(f32x2 a, f32x2 b, f32x2 c) {
    f32x2 d;
    asm("v_pk_fma_f32 %0, %1, %2, %3 clamp" : "=v"(d) : "v"(a), "v"(b), "s"(c));
    return d;
}

// Process 8 f32x2 pairs (16 elems) through all 16 steps.
__device__ __forceinline__ void spike8(f32x2 v[8], f32x2 o[8]) {
    const f32x2 big = {kBIG, kBIG};   // hoisted VGPR pair
    f32x2 z[8];
    {   // t = 0: z_{-1}=0 so v unchanged; o = z*D0.
        const f32x2 ts = {-kT[0] * kBIG, -kT[0] * kBIG};
        const f32x2 dd = {kD[0], kD[0]};
        const f32x2 zz = {0.0f, 0.0f};
#pragma unroll
        for (int c = 0; c < 8; ++c) {
            z[c] = pk_fma_clamp_s(v[c], big, ts);   // z = (v>T0)
            o[c] = pk_fma_s(z[c], dd, zz);          // o = z*D0 (exact)
        }
    }
#pragma unroll
    for (int t = 1; t < 16; ++t) {
        const f32x2 nh = {-kH[t], -kH[t]};
        const f32x2 ts = {-kT[t] * kBIG, -kT[t] * kBIG};
        const f32x2 dd = {kD[t], kD[t]};
#pragma unroll
        for (int c = 0; c < 8; ++c) {
            v[c] = pk_fma_s(z[c], nh, v[c]);        // v -= z_{t-1}*H[t]
            z[c] = pk_fma_clamp_s(v[c], big, ts);   // z = (v>T[t])
            o[c] = pk_fma_s(z[c], dd, o[c]);        // o += z*D[t]
        }
    }
}

// Exact-cover fast path: each thread owns 4 f32x4 at stride T.
__global__ __launch_bounds__(256) void spike_kernel(const f32x4* __restrict__ x,
                                                    f32x4* __restrict__ out) {
    const int T = gridDim.x * blockDim.x;
    const int i = blockIdx.x * blockDim.x + threadIdx.x;

    f32x4 a0 = x[i];
    f32x4 a1 = x[i + T];
    f32x4 a2 = x[i + 2 * T];
    f32x4 a3 = x[i + 3 * T];

    f32x2 v[8] = {a0.xy, a0.zw, a1.xy, a1.zw, a2.xy, a2.zw, a3.xy, a3.zw};
    f32x2 o[8];
    spike8(v, o);

    f32x4 r0 = {o[0].x, o[0].y, o[1].x, o[1].y};
    f32x4 r1 = {o[2].x, o[2].y, o[3].x, o[3].y};
    f32x4 r2 = {o[4].x, o[4].y, o[5].x, o[5].y};
    f32x4 r3 = {o[6].x, o[6].y, o[7].x, o[7].y};

    __builtin_nontemporal_store(r0, &out[i]);
    __builtin_nontemporal_store(r1, &out[i + T]);
    __builtin_nontemporal_store(r2, &out[i + 2 * T]);
    __builtin_nontemporal_store(r3, &out[i + 3 * T]);
}

// Generic fallback (any n4), plain math — reference-exact.
__device__ __forceinline__ float spike_chain(float v) {
    float z = (v > kT[0]) ? 1.0f : 0.0f;
    float out = z * kD[0];
#pragma unroll
    for (int t = 1; t < 16; ++t) {
        v = fmaf(-z, kH[t], v);
        z = (v > kT[t]) ? 1.0f : 0.0f;
        out = fmaf(z, kD[t], out);
    }
    return out;
}

__global__ __launch_bounds__(256) void spike_generic(const f32x4* __restrict__ x,
                                                     f32x4* __restrict__ out,
                                                     int n4) {
    const int T = gridDim.x * blockDim.x;
    int i = blockIdx.x * blockDim.x + threadIdx.x;
    for (; i < n4; i += T) {
        f32x4 a = x[i];
        f32x4 r;
        r.x = spike_chain(a.x);
        r.y = spike_chain(a.y);
        r.z = spike_chain(a.z);
        r.w = spike_chain(a.w);
        __builtin_nontemporal_store(r, &out[i]);
    }
}

extern "C" void kernel_launch(void* const* d_in, const int* in_sizes, int n_in,
                              void* d_out, int out_size, void* d_ws, size_t ws_size,
                              hipStream_t stream) {
    const float* x = (const float*)d_in[0];
    float* out = (float*)d_out;
    int n = in_sizes[0];          // 16*4096*1024 = 67,108,864
    int n4 = n >> 2;              // 16,777,216 float4

    const int block = 256;
    const int per_thread = 4;     // f32x4 per thread

    if (n4 % (block * per_thread) == 0) {
        int grid = n4 / (block * per_thread);   // 16384 for the bench shape
        spike_kernel<<<grid, block, 0, stream>>>(
            (const f32x4*)x, (f32x4*)out);
    } else {
        int grid = (n4 + block - 1) / block;
        if (grid > 4096) grid = 4096;
        spike_generic<<<grid, block, 0, stream>>>(
            (const f32x4*)x, (f32x4*)out, n4);
    }
}

// Round 11
// 82.188 us; speedup vs baseline: 1.3508x; 1.0063x over previous
//
#include <hip/hip_runtime.h>

// 16-step spike recurrence, elementwise.
// z_t = (v_t > T_t) since (v-T)/(|v|+1) > 0 <=> v > T (denominator >= 1).
// R11: single-variable A/B vs R10 — stores emitted as
//   global_store_dwordx4 ... nt sc1   (non-temporal + device scope)
// Hypothesis: plain `nt` stores still ALLOCATE in the 256 MiB L3 and evict
// half of the exactly-256-MiB input each replay (FETCH stuck at ~131 MB in
// every round). Write-around stores should leave x L3-resident: FETCH -> ~0,
// HBM traffic ~writes-only, dur toward ~65-70us.
// Everything else identical to R10 (pk-fma+clamp, SGPR consts, 16384 blocks).

typedef float f32x2 __attribute__((ext_vector_type(2)));
typedef float f32x4 __attribute__((ext_vector_type(4)));

static constexpr float kBIG = 1099511627776.0f;  // 2^40 (exact scale)

static constexpr float kH[16] = {
    -0.73437643f, 3.319645f,   2.1290164f,  3.6901689f,
    3.302721f,    3.2154958f,  2.9151256f,  3.1718695f,
    3.1084518f,   2.6179547f,  2.235003f,   1.2864777f,
    0.52327204f, -0.08344932f, -1.8249638f, 3.0859442f};

static constexpr float kD[16] = {
    3.3848417f, -0.07072583f, 3.691287f,   3.3074934f,
    3.2120926f,  2.9196491f,  3.1727686f,  3.1054153f,
    2.621943f,   2.2355895f,  1.2878408f,  0.52468026f,
    0.12632068f, 0.14482783f, 0.3153498f,  0.13054803f};

static constexpr float kT[16] = {
    3.1538513f, -1.0211663f,  1.3714716f,  1.0718397f,
    1.0049332f,  0.68078244f, 1.0151638f,  0.8858697f,
    0.4037103f,  0.01490025f, -0.90781677f, -1.6859558f,
    -1.9241625f, -2.0441303f, 0.279356f,   0.1315174f};

// a,c in VGPRs; b is a wave-uniform constant pair in SGPRs (scalar pipe).
__device__ __forceinline__ f32x2 pk_fma_s(f32x2 a, f32x2 b, f32x2 c) {
    f32x2 d;
    asm("v_pk_fma_f32 %0, %1, %2, %3" : "=v"(d) : "v"(a), "s"(b), "v"(c));
    return d;
}

// z = clamp(a*b + c): a,b in VGPRs (b = hoisted 2^40 pair), c SGPR constant.
__device__ __forceinline__ f32x2 pk_fma_clamp_s(f32x2 a, f32x2 b, f32x2 c) {
    f32x2 d;
    asm("v_pk_fma_f32 %0, %1, %2, %3 clamp" : "=v"(d) : "v"(a), "v"(b), "s"(c));
    return d;
}

// Non-temporal, non-allocating (write-around L3) 16B store.
__device__ __forceinline__ void store_nt_bypass(f32x4* p, f32x4 v) {
    asm volatile("global_store_dwordx4 %0, %1, off nt sc1"
                 :: "v"(p), "v"(v) : "memory");
}

// Process 8 f32x2 pairs (16 elems) through all 16 steps.
__device__ __forceinline__ void spike8(f32x2 v[8], f32x2 o[8]) {
    const f32x2 big = {kBIG, kBIG};   // hoisted VGPR pair
    f32x2 z[8];
    {   // t = 0: z_{-1}=0 so v unchanged; o = z*D0.
        const f32x2 ts = {-kT[0] * kBIG, -kT[0] * kBIG};
        const f32x2 dd = {kD[0], kD[0]};
        const f32x2 zz = {0.0f, 0.0f};
#pragma unroll
        for (int c = 0; c < 8; ++c) {
            z[c] = pk_fma_clamp_s(v[c], big, ts);   // z = (v>T0)
            o[c] = pk_fma_s(z[c], dd, zz);          // o = z*D0 (exact)
        }
    }
#pragma unroll
    for (int t = 1; t < 16; ++t) {
        const f32x2 nh = {-kH[t], -kH[t]};
        const f32x2 ts = {-kT[t] * kBIG, -kT[t] * kBIG};
        const f32x2 dd = {kD[t], kD[t]};
#pragma unroll
        for (int c = 0; c < 8; ++c) {
            v[c] = pk_fma_s(z[c], nh, v[c]);        // v -= z_{t-1}*H[t]
            z[c] = pk_fma_clamp_s(v[c], big, ts);   // z = (v>T[t])
            o[c] = pk_fma_s(z[c], dd, o[c]);        // o += z*D[t]
        }
    }
}

// Exact-cover fast path: each thread owns 4 f32x4 at stride T.
__global__ __launch_bounds__(256) void spike_kernel(const f32x4* __restrict__ x,
                                                    f32x4* __restrict__ out) {
    const int T = gridDim.x * blockDim.x;
    const int i = blockIdx.x * blockDim.x + threadIdx.x;

    f32x4 a0 = x[i];
    f32x4 a1 = x[i + T];
    f32x4 a2 = x[i + 2 * T];
    f32x4 a3 = x[i + 3 * T];

    f32x2 v[8] = {a0.xy, a0.zw, a1.xy, a1.zw, a2.xy, a2.zw, a3.xy, a3.zw};
    f32x2 o[8];
    spike8(v, o);

    f32x4 r0 = {o[0].x, o[0].y, o[1].x, o[1].y};
    f32x4 r1 = {o[2].x, o[2].y, o[3].x, o[3].y};
    f32x4 r2 = {o[4].x, o[4].y, o[5].x, o[5].y};
    f32x4 r3 = {o[6].x, o[6].y, o[7].x, o[7].y};

    store_nt_bypass(&out[i], r0);
    store_nt_bypass(&out[i + T], r1);
    store_nt_bypass(&out[i + 2 * T], r2);
    store_nt_bypass(&out[i + 3 * T], r3);
}

// Generic fallback (any n4), plain math — reference-exact.
__device__ __forceinline__ float spike_chain(float v) {
    float z = (v > kT[0]) ? 1.0f : 0.0f;
    float out = z * kD[0];
#pragma unroll
    for (int t = 1; t < 16; ++t) {
        v = fmaf(-z, kH[t], v);
        z = (v > kT[t]) ? 1.0f : 0.0f;
        out = fmaf(z, kD[t], out);
    }
    return out;
}

__global__ __launch_bounds__(256) void spike_generic(const f32x4* __restrict__ x,
                                                     f32x4* __restrict__ out,
                                                     int n4) {
    const int T = gridDim.x * blockDim.x;
    int i = blockIdx.x * blockDim.x + threadIdx.x;
    for (; i < n4; i += T) {
        f32x4 a = x[i];
        f32x4 r;
        r.x = spike_chain(a.x);
        r.y = spike_chain(a.y);
        r.z = spike_chain(a.z);
        r.w = spike_chain(a.w);
        __builtin_nontemporal_store(r, &out[i]);
    }
}

extern "C" void kernel_launch(void* const* d_in, const int* in_sizes, int n_in,
                              void* d_out, int out_size, void* d_ws, size_t ws_size,
                              hipStream_t stream) {
    const float* x = (const float*)d_in[0];
    float* out = (float*)d_out;
    int n = in_sizes[0];          // 16*4096*1024 = 67,108,864
    int n4 = n >> 2;              // 16,777,216 float4

    const int block = 256;
    const int per_thread = 4;     // f32x4 per thread

    if (n4 % (block * per_thread) == 0) {
        int grid = n4 / (block * per_thread);   // 16384 for the bench shape
        spike_kernel<<<grid, block, 0, stream>>>(
            (const f32x4*)x, (f32x4*)out);
    } else {
        int grid = (n4 + block - 1) / block;
        if (grid > 4096) grid = 4096;
        spike_generic<<<grid, block, 0, stream>>>(
            (const f32x4*)x, (f32x4*)out, n4);
    }
}

// Round 14
// 82.028 us; speedup vs baseline: 1.3534x; 1.0020x over previous
//
#include <hip/hip_runtime.h>

// 16-step spike recurrence, elementwise.
// z_t = (v_t > T_t) since (v-T)/(|v|+1) > 0 <=> v > T (denominator >= 1).
// FINAL (= R11, best passing: 82.19 us):
//  - pk-fma formulation: z = clamp(fma(v, 2^40, -T*2^40)) via
//    v_pk_fma_f32 ... clamp (no compare/select); all updates packed fma.
//    Bit-exact vs reference (z in {0,1} => every fma single-rounded
//    identically; sign of scaled fma exact).
//  - nontemporal non-allocating stores (global_store_dwordx4 nt sc1):
//    R9 A/B showed cached stores cost +27us; WRITE_SIZE exactly minimal.
//  - exact-cover grid: 16384 blocks x 256 threads, 4x f32x4 per thread.
// Roofline evidence: app-level BW 6.5 TB/s >= 6.29 TB/s copy ceiling;
// VALU-issue 41us << wall; last VALU cut (44->41us) moved wall ~1%.

typedef float f32x2 __attribute__((ext_vector_type(2)));
typedef float f32x4 __attribute__((ext_vector_type(4)));

static constexpr float kBIG = 1099511627776.0f;  // 2^40 (exact scale)

static constexpr float kH[16] = {
    -0.73437643f, 3.319645f,   2.1290164f,  3.6901689f,
    3.302721f,    3.2154958f,  2.9151256f,  3.1718695f,
    3.1084518f,   2.6179547f,  2.235003f,   1.2864777f,
    0.52327204f, -0.08344932f, -1.8249638f, 3.0859442f};

static constexpr float kD[16] = {
    3.3848417f, -0.07072583f, 3.691287f,   3.3074934f,
    3.2120926f,  2.9196491f,  3.1727686f,  3.1054153f,
    2.621943f,   2.2355895f,  1.2878408f,  0.52468026f,
    0.12632068f, 0.14482783f, 0.3153498f,  0.13054803f};

static constexpr float kT[16] = {
    3.1538513f, -1.0211663f,  1.3714716f,  1.0718397f,
    1.0049332f,  0.68078244f, 1.0151638f,  0.8858697f,
    0.4037103f,  0.01490025f, -0.90781677f, -1.6859558f,
    -1.9241625f, -2.0441303f, 0.279356f,   0.1315174f};

// a,c in VGPRs; b is a wave-uniform constant pair in SGPRs (scalar pipe).
__device__ __forceinline__ f32x2 pk_fma_s(f32x2 a, f32x2 b, f32x2 c) {
    f32x2 d;
    asm("v_pk_fma_f32 %0, %1, %2, %3" : "=v"(d) : "v"(a), "s"(b), "v"(c));
    return d;
}

// z = clamp(a*b + c): a,b in VGPRs (b = hoisted 2^40 pair), c SGPR constant.
__device__ __forceinline__ f32x2 pk_fma_clamp_s(f32x2 a, f32x2 b, f32x2 c) {
    f32x2 d;
    asm("v_pk_fma_f32 %0, %1, %2, %3 clamp" : "=v"(d) : "v"(a), "v"(b), "s"(c));
    return d;
}

// Non-temporal, non-allocating (write-around) 16B store.
__device__ __forceinline__ void store_nt(f32x4* p, f32x4 v) {
    asm volatile("global_store_dwordx4 %0, %1, off nt sc1"
                 :: "v"(p), "v"(v) : "memory");
}

// Process 8 f32x2 pairs (16 elems) through all 16 steps.
__device__ __forceinline__ void spike8(f32x2 v[8], f32x2 o[8]) {
    const f32x2 big = {kBIG, kBIG};   // hoisted VGPR pair
    f32x2 z[8];
    {   // t = 0: z_{-1}=0 so v unchanged; o = z*D0.
        const f32x2 ts = {-kT[0] * kBIG, -kT[0] * kBIG};
        const f32x2 dd = {kD[0], kD[0]};
        const f32x2 zz = {0.0f, 0.0f};
#pragma unroll
        for (int c = 0; c < 8; ++c) {
            z[c] = pk_fma_clamp_s(v[c], big, ts);   // z = (v>T0)
            o[c] = pk_fma_s(z[c], dd, zz);          // o = z*D0 (exact)
        }
    }
#pragma unroll
    for (int t = 1; t < 16; ++t) {
        const f32x2 nh = {-kH[t], -kH[t]};
        const f32x2 ts = {-kT[t] * kBIG, -kT[t] * kBIG};
        const f32x2 dd = {kD[t], kD[t]};
#pragma unroll
        for (int c = 0; c < 8; ++c) {
            v[c] = pk_fma_s(z[c], nh, v[c]);        // v -= z_{t-1}*H[t]
            z[c] = pk_fma_clamp_s(v[c], big, ts);   // z = (v>T[t])
            o[c] = pk_fma_s(z[c], dd, o[c]);        // o += z*D[t]
        }
    }
}

// Exact-cover fast path: each thread owns 4 f32x4 at stride T.
__global__ __launch_bounds__(256) void spike_kernel(const f32x4* __restrict__ x,
                                                    f32x4* __restrict__ out) {
    const int T = gridDim.x * blockDim.x;
    const int i = blockIdx.x * blockDim.x + threadIdx.x;

    f32x4 a0 = x[i];
    f32x4 a1 = x[i + T];
    f32x4 a2 = x[i + 2 * T];
    f32x4 a3 = x[i + 3 * T];

    f32x2 v[8] = {a0.xy, a0.zw, a1.xy, a1.zw, a2.xy, a2.zw, a3.xy, a3.zw};
    f32x2 o[8];
    spike8(v, o);

    f32x4 r0 = {o[0].x, o[0].y, o[1].x, o[1].y};
    f32x4 r1 = {o[2].x, o[2].y, o[3].x, o[3].y};
    f32x4 r2 = {o[4].x, o[4].y, o[5].x, o[5].y};
    f32x4 r3 = {o[6].x, o[6].y, o[7].x, o[7].y};

    store_nt(&out[i], r0);
    store_nt(&out[i + T], r1);
    store_nt(&out[i + 2 * T], r2);
    store_nt(&out[i + 3 * T], r3);
}

// Generic fallback (any n4), plain math — reference-exact.
__device__ __forceinline__ float spike_chain(float v) {
    float z = (v > kT[0]) ? 1.0f : 0.0f;
    float out = z * kD[0];
#pragma unroll
    for (int t = 1; t < 16; ++t) {
        v = fmaf(-z, kH[t], v);
        z = (v > kT[t]) ? 1.0f : 0.0f;
        out = fmaf(z, kD[t], out);
    }
    return out;
}

__global__ __launch_bounds__(256) void spike_generic(const f32x4* __restrict__ x,
                                                     f32x4* __restrict__ out,
                                                     int n4) {
    const int T = gridDim.x * blockDim.x;
    int i = blockIdx.x * blockDim.x + threadIdx.x;
    for (; i < n4; i += T) {
        f32x4 a = x[i];
        f32x4 r;
        r.x = spike_chain(a.x);
        r.y = spike_chain(a.y);
        r.z = spike_chain(a.z);
        r.w = spike_chain(a.w);
        __builtin_nontemporal_store(r, &out[i]);
    }
}

extern "C" void kernel_launch(void* const* d_in, const int* in_sizes, int n_in,
                              void* d_out, int out_size, void* d_ws, size_t ws_size,
                              hipStream_t stream) {
    const float* x = (const float*)d_in[0];
    float* out = (float*)d_out;
    int n = in_sizes[0];          // 16*4096*1024 = 67,108,864
    int n4 = n >> 2;              // 16,777,216 f32x4

    const int block = 256;
    const int per_thread = 4;     // f32x4 per thread

    if (n4 % (block * per_thread) == 0) {
        int grid = n4 / (block * per_thread);   // 16384 for the bench shape
        spike_kernel<<<grid, block, 0, stream>>>(
            (const f32x4*)x, (f32x4*)out);
    } else {
        int grid = (n4 + block - 1) / block;
        if (grid > 4096) grid = 4096;
        spike_generic<<<grid, block, 0, stream>>>(
            (const f32x4*)x, (f32x4*)out, n4);
    }
}